// Round 22
// baseline (486.258 us; speedup 1.0000x reference)
//
#include <hip/hip_runtime.h>

#define NGRAPH 100
#define NPER   1000
#define NNODES 100000
#define NEDGES 1600000
#define EPG    16000   // edges per graph

typedef float v2f  __attribute__((ext_vector_type(2)));
typedef float f32x4 __attribute__((ext_vector_type(4)));
typedef short short8 __attribute__((ext_vector_type(8)));

// DPP-based ops; VALU latency.
template <int CTRL>
__device__ __forceinline__ float dpp_add(float x) {
    int yi = __builtin_amdgcn_update_dpp(0, __float_as_int(x), CTRL, 0xF, 0xF, true);
    return x + __int_as_float(yi);
}
template <int CTRL>
__device__ __forceinline__ float dpp_mov(float x) {
    int yi = __builtin_amdgcn_update_dpp(0, __float_as_int(x), CTRL, 0xF, 0xF, true);
    return __int_as_float(yi);
}
#define DPP_XOR1 0xB1   // quad_perm [1,0,3,2]
#define DPP_XOR2 0x4E   // quad_perm [2,3,0,1]
#define DPP_HMIR 0x141  // row_half_mirror

// bf16x2 (packed in u32) -> 2 floats
__device__ __forceinline__ v2f bf2f(unsigned u) {
    v2f r;
    r.x = __uint_as_float(u << 16);
    r.y = __uint_as_float(u & 0xffff0000u);
    return r;
}
// 2 floats -> bf16x2
__device__ __forceinline__ unsigned pkbf(float a, float b) {
    unsigned ua = (__float_as_uint(a) + 0x8000u) >> 16;
    unsigned ub = (__float_as_uint(b) + 0x8000u) & 0xffff0000u;
    return ua | ub;
}
__device__ __forceinline__ short bfs(float x) {
    return (short)((__float_as_uint(x) + 0x8000u) >> 16);
}
__device__ __forceinline__ float bf2f1(short s) {
    return __uint_as_float(((unsigned)(unsigned short)s) << 16);
}

// ==================== utility: zero count + g_acc ====================
__global__ __launch_bounds__(256) void zero2_k(int* __restrict__ count,
                                               float* __restrict__ g_acc) {
    int i = blockIdx.x * 256 + threadIdx.x;
    if (i < NNODES) count[i] = 0;
    if (i < NGRAPH * 96) g_acc[i] = 0.f;
}

// ==================== counting sort of edges by DST ====================
__global__ __launch_bounds__(256) void hist_k(const int* __restrict__ dst,
                                              int* __restrict__ count) {
    int e = blockIdx.x * 256 + threadIdx.x;
    if (e < NEDGES) atomicAdd(&count[dst[e]], 1);
}

__global__ __launch_bounds__(1024) void scan_k(const int* __restrict__ count,
                                               int* __restrict__ offs,
                                               int* __restrict__ cursor) {
    __shared__ int sc[1024];
    int t = threadIdx.x, g = blockIdx.x;
    int v = (t < NPER) ? count[g * NPER + t] : 0;
    sc[t] = v;
    __syncthreads();
    for (int s = 1; s < 1024; s <<= 1) {
        int add = (t >= s) ? sc[t - s] : 0;
        __syncthreads();
        sc[t] += add;
        __syncthreads();
    }
    if (t < NPER) {
        int start = g * EPG + sc[t] - v;   // exclusive
        offs[g * NPER + t]   = start;
        cursor[g * NPER + t] = start;
    }
}

// compressed record: {src*16, etype | elabel<<16}
__global__ __launch_bounds__(256) void scatter_k(
    const int* __restrict__ src, const int* __restrict__ dst,
    const int* __restrict__ et, const int* __restrict__ el,
    int* __restrict__ cursor, int2* __restrict__ sorted2) {
    int e = blockIdx.x * 256 + threadIdx.x;
    if (e >= NEDGES) return;
    int d = dst[e];
    int p = atomicAdd(&cursor[d], 1);
    sorted2[p] = make_int2(src[e] * 16, et[e] | (el[e] << 16));
}

// ==================== B-fragment precompute (all layers) ====================
__global__ __launch_bounds__(64) void wfrag_k(
    const float* __restrict__ basis, const float* __restrict__ selfw,
    const float* __restrict__ A_w, uint4* __restrict__ bfrag)
{
    int t = blockIdx.x;          // tile 0..13
    int l = blockIdx.y;          // layer
    int ln = threadIdx.x;
    int j = ln & 15, grp = ln >> 4;
    int n = t * 16 + j;
    int mat = n >> 5, o = n & 31;
    const float* W;
    if (mat < 4)       W = basis + l * 4096 + mat * 1024;
    else if (mat == 4) W = A_w + l * 4096;            // A1: rows 0..31
    else if (mat == 5) W = A_w + l * 4096 + 1024;     // A2: rows 32..63
    else               W = selfw + l * 1024;
    unsigned w0 = pkbf(W[(grp*8+0)*32 + o], W[(grp*8+1)*32 + o]);
    unsigned w1 = pkbf(W[(grp*8+2)*32 + o], W[(grp*8+3)*32 + o]);
    unsigned w2 = pkbf(W[(grp*8+4)*32 + o], W[(grp*8+5)*32 + o]);
    unsigned w3 = pkbf(W[(grp*8+6)*32 + o], W[(grp*8+7)*32 + o]);
    bfrag[(l * 14 + t) * 64 + ln] = make_uint4(w0, w1, w2, w3);
}

// ==================== rel tables (all layers) ====================
__global__ __launch_bounds__(256) void rel3_k(
    const float* __restrict__ attn_tab, const float* __restrict__ A_w,
    const float* __restrict__ A_b, unsigned* __restrict__ t1b,
    unsigned* __restrict__ t2b)
{
    int l = blockIdx.y;
    int r = blockIdx.x * 4 + (threadIdx.x >> 6);
    if (r >= 200) return;
    int t = threadIdx.x & 63;
    int o = t & 31;
    bool second = t >= 32;
    const float* at = attn_tab + r * 32;
    const float* W  = A_w + l * 4096 + (second ? 96*32 : 64*32);
    float acc = second ? 0.f : A_b[l*32 + o];
    #pragma unroll 8
    for (int d = 0; d < 32; d++) acc += at[d] * W[d*32 + o];
    float nb = __shfl_down(acc, 1);
    unsigned u = pkbf(acc, nb);
    if (!(o & 1)) (second ? t2b : t1b)[l*3200 + r*16 + (o >> 1)] = u;
}

// ==================== MFMA node projections ====================
__global__ __launch_bounds__(256, 4) void node_mfma_k(
    const float* __restrict__ h, const uint4* __restrict__ bfrag_l,
    uint4* __restrict__ xproj_b, float* __restrict__ psrc,
    float* __restrict__ pdst, float* __restrict__ selfp)
{
    const int wave = threadIdx.x >> 6;
    const int lane = threadIdx.x & 63;
    const int base = blockIdx.x * 64 + wave * 16;
    const int j    = lane & 15;
    const int grp  = lane >> 4;
    const int par  = j & 1;

    int m = base + j;
    int mc = (m < NNODES) ? m : NNODES - 1;
    const float4* hp = (const float4*)(h + mc * 32 + grp * 8);
    float4 h0 = hp[0], h1 = hp[1];
    float hf[8] = {h0.x, h0.y, h0.z, h0.w, h1.x, h1.y, h1.z, h1.w};
    short8 ahi, alo;
    #pragma unroll
    for (int s = 0; s < 8; s++) {
        short hi = bfs(hf[s]);
        ahi[s] = hi;
        alo[s] = bfs(hf[s] - bf2f1(hi));
    }

    const f32x4 zero = {0.f, 0.f, 0.f, 0.f};

    #pragma unroll 1
    for (int t = 8; t < 14; t++) {
        uint4 braw = bfrag_l[t * 64 + lane];
        short8 b = *(short8*)&braw;
        f32x4 d = __builtin_amdgcn_mfma_f32_16x16x32_bf16(ahi, b, zero, 0, 0, 0);
        d = __builtin_amdgcn_mfma_f32_16x16x32_bf16(alo, b, d, 0, 0, 0);
        float* outp = (t < 10) ? psrc : (t < 12) ? pdst : selfp;
        int ch = (t & 1) * 16 + j;
        #pragma unroll
        for (int q = 0; q < 4; q++) {
            int mq = base + grp * 4 + q;
            if (mq < NNODES) outp[mq * 32 + ch] = d[q];
        }
    }

    f32x4 db[8];
    #pragma unroll 1
    for (int t = 0; t < 8; t++) {
        uint4 braw = bfrag_l[t * 64 + lane];
        short8 b = *(short8*)&braw;
        f32x4 d = __builtin_amdgcn_mfma_f32_16x16x32_bf16(ahi, b, zero, 0, 0, 0);
        db[t] = __builtin_amdgcn_mfma_f32_16x16x32_bf16(alo, b, d, 0, 0, 0);
    }
    #pragma unroll
    for (int q = 0; q < 4; q++) {
        int mq = base + grp * 4 + q;
        unsigned pk[4];
        #pragma unroll
        for (int b2 = 0; b2 < 4; b2++) {
            float v0 = db[2*b2][q];
            float v1 = db[2*b2 + 1][q];
            float o0 = dpp_mov<DPP_XOR1>(v0);
            float o1 = dpp_mov<DPP_XOR1>(v1);
            pk[b2] = par ? pkbf(o1, v1) : pkbf(v0, o0);
        }
        if (mq < NNODES)
            xproj_b[mq * 16 + par * 8 + (j >> 1)] =
                make_uint4(pk[0], pk[1], pk[2], pk[3]);
    }
}

// ==================== CSR edge kernel: 8 lanes/edge, 2-deep pipeline =======
// R22: two 8-edge groups per loop trip; all 12 data gathers issue before
// either compute -> one latency exposure for deg<=16 waves (the majority).
// Lane mapping unchanged from the R14 local optimum.
__global__ __launch_bounds__(256) void edge_csr_k(
    const int2* __restrict__ sorted2, const int* __restrict__ offs,
    const float* __restrict__ psrc, const float* __restrict__ pdst,
    const unsigned* __restrict__ t1b, const unsigned* __restrict__ t2b,
    const uint4* __restrict__ xproj_b, const float* __restrict__ selfp,
    const float* __restrict__ wcomp_l,
    const float* __restrict__ Bw, const float* __restrict__ Bb,
    float* __restrict__ h_next)
{
    // XCD-bijective swizzle: 25000 blocks, 25000 % 8 == 0.
    const int CPX = 25000 / 8;
    int bid = (int)blockIdx.x;
    bid = (bid % 8) * CPX + bid / 8;

    const int wib  = threadIdx.x >> 6;
    const int lane = threadIdx.x & 63;
    const int grp  = lane >> 3;          // edge slot 0..7
    const int ci   = lane & 7;           // channel quad 0..7
    const int c4   = ci * 4;
    const int n    = bid * 4 + wib;

    const int start = offs[n];
    const int end   = (n == NNODES - 1) ? NEDGES : offs[n + 1];
    const float4 bw = *(const float4*)(Bw + c4);
    const float bb = Bb[0];
    const float4 pd = *(const float4*)(pdst + n * 32 + c4);

    int eA = start + grp;
    int eB = eA + 8;
    int2 recA = sorted2[(eA < end) ? eA : start];
    int2 recB = sorted2[(eB < end) ? eB : start];
    bool vA = (eA < end);
    bool vB = (eB < end);

    v2f acc01 = {0.f, 0.f}, acc23 = {0.f, 0.f};
    for (int e0 = start; e0 < end; e0 += 16) {
        int2 cA = recA; bool cvA = vA;
        int2 cB = recB; bool cvB = vB;
        int enA = eA + 16, enB = eB + 16;
        vA = (enA < end);
        vB = (enB < end);
        recA = sorted2[vA ? enA : start];
        recB = sorted2[vB ? enB : start];
        eA = enA; eB = enB;

        int sA = cA.x, etA = cA.y & 0xffff, elA = cA.y >> 16;
        int sB = cB.x, etB = cB.y & 0xffff, elB = cB.y >> 16;

        // ---- all 12 data gathers issue here ----
        float4 psA  = *(const float4*)(psrc + sA * 2 + c4);
        uint4  xloA = xproj_b[sA + ci * 2];
        uint4  xhiA = xproj_b[sA + ci * 2 + 1];
        uint2  t1A  = *(const uint2*)(t1b + etA * 16 + ci * 2);
        uint2  t2A  = *(const uint2*)(t2b + elA * 16 + ci * 2);
        float4 ccA  = *(const float4*)(wcomp_l + etA * 4);
        float4 psB  = *(const float4*)(psrc + sB * 2 + c4);
        uint4  xloB = xproj_b[sB + ci * 2];
        uint4  xhiB = xproj_b[sB + ci * 2 + 1];
        uint2  t1B  = *(const uint2*)(t1b + etB * 16 + ci * 2);
        uint2  t2B  = *(const uint2*)(t2b + elB * 16 + ci * 2);
        float4 ccB  = *(const float4*)(wcomp_l + etB * 4);

        // ---- compute group A ----
        {
            v2f t1a = bf2f(t1A.x), t1c = bf2f(t1A.y);
            v2f t2a = bf2f(t2A.x), t2c = bf2f(t2A.y);
            float z0 = fmaxf(psA.x + pd.x + t1a.x + t2a.x, 0.f);
            float z1 = fmaxf(psA.y + pd.y + t1a.y + t2a.y, 0.f);
            float z2 = fmaxf(psA.z + pd.z + t1c.x + t2c.x, 0.f);
            float z3 = fmaxf(psA.w + pd.w + t1c.y + t2c.y, 0.f);
            float d = fmaf(z0, bw.x, fmaf(z1, bw.y, fmaf(z2, bw.z, z3 * bw.w)));
            d = dpp_add<DPP_XOR1>(d);
            d = dpp_add<DPP_XOR2>(d);
            d = dpp_add<DPP_HMIR>(d);
            float a = __builtin_amdgcn_rcpf(1.f + __expf(-(d + bb)));
            a = cvA ? a : 0.f;
            v2f b0 = bf2f(xloA.x), b1 = bf2f(xloA.y), b2 = bf2f(xloA.z), b3 = bf2f(xloA.w);
            v2f m01 = ccA.x * b0 + ccA.y * b1 + ccA.z * b2 + ccA.w * b3;
            v2f g0 = bf2f(xhiA.x), g1 = bf2f(xhiA.y), g2 = bf2f(xhiA.z), g3 = bf2f(xhiA.w);
            v2f m23 = ccA.x * g0 + ccA.y * g1 + ccA.z * g2 + ccA.w * g3;
            acc01 += a * m01;
            acc23 += a * m23;
        }
        // ---- compute group B ----
        {
            v2f t1a = bf2f(t1B.x), t1c = bf2f(t1B.y);
            v2f t2a = bf2f(t2B.x), t2c = bf2f(t2B.y);
            float z0 = fmaxf(psB.x + pd.x + t1a.x + t2a.x, 0.f);
            float z1 = fmaxf(psB.y + pd.y + t1a.y + t2a.y, 0.f);
            float z2 = fmaxf(psB.z + pd.z + t1c.x + t2c.x, 0.f);
            float z3 = fmaxf(psB.w + pd.w + t1c.y + t2c.y, 0.f);
            float d = fmaf(z0, bw.x, fmaf(z1, bw.y, fmaf(z2, bw.z, z3 * bw.w)));
            d = dpp_add<DPP_XOR1>(d);
            d = dpp_add<DPP_XOR2>(d);
            d = dpp_add<DPP_HMIR>(d);
            float a = __builtin_amdgcn_rcpf(1.f + __expf(-(d + bb)));
            a = cvB ? a : 0.f;
            v2f b0 = bf2f(xloB.x), b1 = bf2f(xloB.y), b2 = bf2f(xloB.z), b3 = bf2f(xloB.w);
            v2f m01 = ccB.x * b0 + ccB.y * b1 + ccB.z * b2 + ccB.w * b3;
            v2f g0 = bf2f(xhiB.x), g1 = bf2f(xhiB.y), g2 = bf2f(xhiB.z), g3 = bf2f(xhiB.w);
            v2f m23 = ccB.x * g0 + ccB.y * g1 + ccB.z * g2 + ccB.w * g3;
            acc01 += a * m01;
            acc23 += a * m23;
        }
    }
    #pragma unroll
    for (int s = 8; s <= 32; s <<= 1) {
        acc01.x += __shfl_xor(acc01.x, s);
        acc01.y += __shfl_xor(acc01.y, s);
        acc23.x += __shfl_xor(acc23.x, s);
        acc23.y += __shfl_xor(acc23.y, s);
    }
    if (lane < 8) {
        float4 sp = *(const float4*)(selfp + n * 32 + c4);
        float4 hv;
        hv.x = fmaxf(acc01.x + sp.x, 0.f);
        hv.y = fmaxf(acc01.y + sp.y, 0.f);
        hv.z = fmaxf(acc23.x + sp.z, 0.f);
        hv.w = fmaxf(acc23.y + sp.w, 0.f);
        *(float4*)(h_next + n * 32 + c4) = hv;
    }
}

// ==================== per-graph mean (8 slices) + head/tail (y=8) ==========
__global__ __launch_bounds__(256) void mean_ht_k(
    const float* __restrict__ h, const int* __restrict__ head_ids,
    const int* __restrict__ tail_ids, float* __restrict__ g_acc,
    float* __restrict__ head_buf, float* __restrict__ tail_buf, int l)
{
    int g  = blockIdx.x;
    int sl = blockIdx.y;
    int i  = threadIdx.x & 31;
    if (sl == 8) {
        if (threadIdx.x < 32)
            head_buf[g*96 + l*32 + i] = h[head_ids[g]*32 + i];
        else if (threadIdx.x < 64)
            tail_buf[g*96 + l*32 + i] = h[tail_ids[g]*32 + i];
        return;
    }
    int sub = threadIdx.x >> 5;
    float acc = 0.f;
    for (int k = sub; k < 125; k += 8)
        acc += h[(g*NPER + sl*125 + k)*32 + i];
    __shared__ float red[8][32];
    red[sub][i] = acc;
    __syncthreads();
    if (threadIdx.x < 32) {
        float s2 = 0.f;
        #pragma unroll
        for (int k = 0; k < 8; k++) s2 += red[k][threadIdx.x];
        atomicAdd(&g_acc[g*96 + l*32 + threadIdx.x], s2 * (1.0f/NPER));
    }
}

// ==================== final readout ====================
__global__ __launch_bounds__(64) void readout_k(
    const float* __restrict__ g_acc, const float* __restrict__ head_buf,
    const float* __restrict__ tail_buf, const float* __restrict__ rel_tab,
    const int* __restrict__ rel_labels, const float* __restrict__ fc_w,
    const float* __restrict__ fc_b, float* __restrict__ out)
{
    int g = blockIdx.x;
    int t = threadIdx.x;
    float s = 0.f;
    for (int idx = t; idx < 320; idx += 64) {
        float v;
        if (idx < 96)       v = g_acc[g*96 + idx];
        else if (idx < 192) v = head_buf[g*96 + idx - 96];
        else if (idx < 288) v = tail_buf[g*96 + idx - 192];
        else                v = rel_tab[rel_labels[g]*32 + (idx - 288)];
        s += v * fc_w[idx];
    }
    s += __shfl_xor(s, 1, 64);
    s += __shfl_xor(s, 2, 64);
    s += __shfl_xor(s, 4, 64);
    s += __shfl_xor(s, 8, 64);
    s += __shfl_xor(s, 16, 64);
    s += __shfl_xor(s, 32, 64);
    if (t == 0) out[g] = s + fc_b[0];
}

extern "C" void kernel_launch(void* const* d_in, const int* in_sizes, int n_in,
                              void* d_out, int out_size, void* d_ws, size_t ws_size,
                              hipStream_t stream) {
    const float* feat        = (const float*)d_in[0];
    const float* basis       = (const float*)d_in[1];   // [3,4,32,32]
    const float* w_comp      = (const float*)d_in[2];   // [3,200,4]
    const float* self_loop_w = (const float*)d_in[3];   // [3,32,32]
    const float* A_w         = (const float*)d_in[4];   // [3,128,32]
    const float* A_b         = (const float*)d_in[5];   // [3,32]
    const float* B_w         = (const float*)d_in[6];   // [3,32,1]
    const float* B_b         = (const float*)d_in[7];   // [3,1]
    const float* attn_tab    = (const float*)d_in[8];   // [200,32]
    const float* rel_tab     = (const float*)d_in[9];   // [200,32]
    const float* fc_w        = (const float*)d_in[10];  // [320,1]
    const float* fc_b        = (const float*)d_in[11];  // [1]
    const int* src        = (const int*)d_in[12];
    const int* dst        = (const int*)d_in[13];
    const int* etype      = (const int*)d_in[14];
    const int* elabel     = (const int*)d_in[15];
    const int* head_ids   = (const int*)d_in[17];
    const int* tail_ids   = (const int*)d_in[18];
    const int* rel_labels = (const int*)d_in[19];

    float* ws = (float*)d_ws;
    size_t off = 0;
    float* h0    = ws + off; off += (size_t)NNODES * 32;
    float* h1    = ws + off; off += (size_t)NNODES * 32;
    uint4* xproj_b = (uint4*)(ws + off); off += (size_t)NNODES * 64;  // 256B/node
    float* psrc  = ws + off; off += (size_t)NNODES * 32;
    float* pdst  = ws + off; off += (size_t)NNODES * 32;
    float* selfp = ws + off; off += (size_t)NNODES * 32;
    unsigned* t1b = (unsigned*)(ws + off); off += 3 * 3200;
    unsigned* t2b = (unsigned*)(ws + off); off += 3 * 3200;
    uint4* bfrag  = (uint4*)(ws + off);   off += 3 * 14 * 64 * 4;
    float* g_acc    = ws + off; off += NGRAPH * 96;
    float* head_buf = ws + off; off += NGRAPH * 96;
    float* tail_buf = ws + off; off += NGRAPH * 96;
    int* count  = (int*)(ws + off); off += NNODES;
    int* offs   = (int*)(ws + off); off += NNODES;
    int* cursor = (int*)(ws + off); off += NNODES;
    off = (off + 3) & ~(size_t)3;               // 16 B align
    int2* sorted2 = (int2*)(ws + off); off += (size_t)NEDGES * 2;

    // ---- one-time per call: CSR by dst + weight frags + rel tables ----
    zero2_k<<<(NNODES + 255)/256, 256, 0, stream>>>(count, g_acc);
    hist_k<<<(NEDGES + 255)/256, 256, 0, stream>>>(dst, count);
    scan_k<<<NGRAPH, 1024, 0, stream>>>(count, offs, cursor);
    scatter_k<<<(NEDGES + 255)/256, 256, 0, stream>>>(src, dst, etype, elabel,
                                                      cursor, sorted2);
    dim3 wgrid(14, 3);
    wfrag_k<<<wgrid, 64, 0, stream>>>(basis, self_loop_w, A_w, bfrag);
    dim3 rgrid(50, 3);
    rel3_k<<<rgrid, 256, 0, stream>>>(attn_tab, A_w, A_b, t1b, t2b);

    const float* hcur = feat;
    float* hbufs[2] = { h0, h1 };
    for (int l = 0; l < 3; l++) {
        node_mfma_k<<<(NNODES + 63)/64, 256, 0, stream>>>(
            hcur, bfrag + (size_t)l*14*64, xproj_b, psrc, pdst, selfp);
        float* hn = hbufs[l & 1];
        edge_csr_k<<<NNODES/4, 256, 0, stream>>>(
            sorted2, offs, psrc, pdst, t1b + l*3200, t2b + l*3200,
            xproj_b, selfp, w_comp + (size_t)l*800,
            B_w + (size_t)l*32, B_b + l, hn);
        dim3 mgrid(NGRAPH, 9);
        mean_ht_k<<<mgrid, 256, 0, stream>>>(
            hn, head_ids, tail_ids, g_acc, head_buf, tail_buf, l);
        hcur = hn;
    }
    readout_k<<<NGRAPH, 64, 0, stream>>>(
        g_acc, head_buf, tail_buf, rel_tab, rel_labels, fc_w, fc_b, (float*)d_out);
}

// Round 23
// 381.350 us; speedup vs baseline: 1.2751x; 1.2751x over previous
//
#include <hip/hip_runtime.h>

#define NGRAPH 100
#define NPER   1000
#define NNODES 100000
#define NEDGES 1600000
#define EPG    16000   // edges per graph

typedef float v2f  __attribute__((ext_vector_type(2)));
typedef float f32x4 __attribute__((ext_vector_type(4)));
typedef short short8 __attribute__((ext_vector_type(8)));

// DPP-based ops; VALU latency.
template <int CTRL>
__device__ __forceinline__ float dpp_add(float x) {
    int yi = __builtin_amdgcn_update_dpp(0, __float_as_int(x), CTRL, 0xF, 0xF, true);
    return x + __int_as_float(yi);
}
template <int CTRL>
__device__ __forceinline__ float dpp_mov(float x) {
    int yi = __builtin_amdgcn_update_dpp(0, __float_as_int(x), CTRL, 0xF, 0xF, true);
    return __int_as_float(yi);
}
#define DPP_XOR1 0xB1   // quad_perm [1,0,3,2]
#define DPP_XOR2 0x4E   // quad_perm [2,3,0,1]
#define DPP_HMIR 0x141  // row_half_mirror

// bf16x2 (packed in u32) -> 2 floats
__device__ __forceinline__ v2f bf2f(unsigned u) {
    v2f r;
    r.x = __uint_as_float(u << 16);
    r.y = __uint_as_float(u & 0xffff0000u);
    return r;
}
// 2 floats -> bf16x2
__device__ __forceinline__ unsigned pkbf(float a, float b) {
    unsigned ua = (__float_as_uint(a) + 0x8000u) >> 16;
    unsigned ub = (__float_as_uint(b) + 0x8000u) & 0xffff0000u;
    return ua | ub;
}
__device__ __forceinline__ short bfs(float x) {
    return (short)((__float_as_uint(x) + 0x8000u) >> 16);
}
__device__ __forceinline__ float bf2f1(short s) {
    return __uint_as_float(((unsigned)(unsigned short)s) << 16);
}

// ==================== utility: zero count + g_acc ====================
__global__ __launch_bounds__(256) void zero2_k(int* __restrict__ count,
                                               float* __restrict__ g_acc) {
    int i = blockIdx.x * 256 + threadIdx.x;
    if (i < NNODES) count[i] = 0;
    if (i < NGRAPH * 96) g_acc[i] = 0.f;
}

// ==================== counting sort of edges by DST ====================
__global__ __launch_bounds__(256) void hist_k(const int* __restrict__ dst,
                                              int* __restrict__ count) {
    int e = blockIdx.x * 256 + threadIdx.x;
    if (e < NEDGES) atomicAdd(&count[dst[e]], 1);
}

__global__ __launch_bounds__(1024) void scan_k(const int* __restrict__ count,
                                               int* __restrict__ offs,
                                               int* __restrict__ cursor) {
    __shared__ int sc[1024];
    int t = threadIdx.x, g = blockIdx.x;
    int v = (t < NPER) ? count[g * NPER + t] : 0;
    sc[t] = v;
    __syncthreads();
    for (int s = 1; s < 1024; s <<= 1) {
        int add = (t >= s) ? sc[t - s] : 0;
        __syncthreads();
        sc[t] += add;
        __syncthreads();
    }
    if (t < NPER) {
        int start = g * EPG + sc[t] - v;   // exclusive
        offs[g * NPER + t]   = start;
        cursor[g * NPER + t] = start;
    }
}

// compressed record: {src*16, etype | elabel<<16}
__global__ __launch_bounds__(256) void scatter_k(
    const int* __restrict__ src, const int* __restrict__ dst,
    const int* __restrict__ et, const int* __restrict__ el,
    int* __restrict__ cursor, int2* __restrict__ sorted2) {
    int e = blockIdx.x * 256 + threadIdx.x;
    if (e >= NEDGES) return;
    int d = dst[e];
    int p = atomicAdd(&cursor[d], 1);
    sorted2[p] = make_int2(src[e] * 16, et[e] | (el[e] << 16));
}

// ==================== B-fragment precompute (all layers) ====================
// Wcat[k][n], n=0..223: [basis b0..b3 | A1 | A2 | self], each 32 cols.
// B frag (mfma_f32_16x16x32_bf16): lane l holds col n=16t+(l&15),
// k = (l>>4)*8 + s; dword packs k pairs (2s, 2s+1) low/high.
__global__ __launch_bounds__(64) void wfrag_k(
    const float* __restrict__ basis, const float* __restrict__ selfw,
    const float* __restrict__ A_w, uint4* __restrict__ bfrag)
{
    int t = blockIdx.x;          // tile 0..13
    int l = blockIdx.y;          // layer
    int ln = threadIdx.x;
    int j = ln & 15, grp = ln >> 4;
    int n = t * 16 + j;
    int mat = n >> 5, o = n & 31;
    const float* W;
    if (mat < 4)       W = basis + l * 4096 + mat * 1024;
    else if (mat == 4) W = A_w + l * 4096;            // A1: rows 0..31
    else if (mat == 5) W = A_w + l * 4096 + 1024;     // A2: rows 32..63
    else               W = selfw + l * 1024;
    unsigned w0 = pkbf(W[(grp*8+0)*32 + o], W[(grp*8+1)*32 + o]);
    unsigned w1 = pkbf(W[(grp*8+2)*32 + o], W[(grp*8+3)*32 + o]);
    unsigned w2 = pkbf(W[(grp*8+4)*32 + o], W[(grp*8+5)*32 + o]);
    unsigned w3 = pkbf(W[(grp*8+6)*32 + o], W[(grp*8+7)*32 + o]);
    bfrag[(l * 14 + t) * 64 + ln] = make_uint4(w0, w1, w2, w3);
}

// ==================== rel tables (all layers) ====================
__global__ __launch_bounds__(256) void rel3_k(
    const float* __restrict__ attn_tab, const float* __restrict__ A_w,
    const float* __restrict__ A_b, unsigned* __restrict__ t1b,
    unsigned* __restrict__ t2b)
{
    int l = blockIdx.y;
    int r = blockIdx.x * 4 + (threadIdx.x >> 6);
    if (r >= 200) return;
    int t = threadIdx.x & 63;
    int o = t & 31;
    bool second = t >= 32;
    const float* at = attn_tab + r * 32;
    const float* W  = A_w + l * 4096 + (second ? 96*32 : 64*32);
    float acc = second ? 0.f : A_b[l*32 + o];
    #pragma unroll 8
    for (int d = 0; d < 32; d++) acc += at[d] * W[d*32 + o];
    float nb = __shfl_down(acc, 1);
    unsigned u = pkbf(acc, nb);
    if (!(o & 1)) (second ? t2b : t1b)[l*3200 + r*16 + (o >> 1)] = u;
}

// ==================== MFMA node projections ====================
// Wave: 16 nodes x 224 outputs. A split hi/lo for f32-grade accuracy on h.
// D layout (m89): col n = lane&15, node row = (lane>>4)*4 + reg.
__global__ __launch_bounds__(256, 4) void node_mfma_k(
    const float* __restrict__ h, const uint4* __restrict__ bfrag_l,
    uint4* __restrict__ xproj_b, float* __restrict__ psrc,
    float* __restrict__ pdst, float* __restrict__ selfp)
{
    const int wave = threadIdx.x >> 6;
    const int lane = threadIdx.x & 63;
    const int base = blockIdx.x * 64 + wave * 16;
    const int j    = lane & 15;
    const int grp  = lane >> 4;
    const int par  = j & 1;

    int m = base + j;
    int mc = (m < NNODES) ? m : NNODES - 1;
    const float4* hp = (const float4*)(h + mc * 32 + grp * 8);
    float4 h0 = hp[0], h1 = hp[1];
    float hf[8] = {h0.x, h0.y, h0.z, h0.w, h1.x, h1.y, h1.z, h1.w};
    short8 ahi, alo;
    #pragma unroll
    for (int s = 0; s < 8; s++) {
        short hi = bfs(hf[s]);
        ahi[s] = hi;
        alo[s] = bfs(hf[s] - bf2f1(hi));
    }

    const f32x4 zero = {0.f, 0.f, 0.f, 0.f};

    #pragma unroll 1
    for (int t = 8; t < 14; t++) {
        uint4 braw = bfrag_l[t * 64 + lane];
        short8 b = *(short8*)&braw;
        f32x4 d = __builtin_amdgcn_mfma_f32_16x16x32_bf16(ahi, b, zero, 0, 0, 0);
        d = __builtin_amdgcn_mfma_f32_16x16x32_bf16(alo, b, d, 0, 0, 0);
        float* outp = (t < 10) ? psrc : (t < 12) ? pdst : selfp;
        int ch = (t & 1) * 16 + j;
        #pragma unroll
        for (int q = 0; q < 4; q++) {
            int mq = base + grp * 4 + q;
            if (mq < NNODES) outp[mq * 32 + ch] = d[q];
        }
    }

    f32x4 db[8];
    #pragma unroll 1
    for (int t = 0; t < 8; t++) {
        uint4 braw = bfrag_l[t * 64 + lane];
        short8 b = *(short8*)&braw;
        f32x4 d = __builtin_amdgcn_mfma_f32_16x16x32_bf16(ahi, b, zero, 0, 0, 0);
        db[t] = __builtin_amdgcn_mfma_f32_16x16x32_bf16(alo, b, d, 0, 0, 0);
    }
    // exchange BOTH channel-halves via DPP, THEN select by parity (R21 fix)
    #pragma unroll
    for (int q = 0; q < 4; q++) {
        int mq = base + grp * 4 + q;
        unsigned pk[4];
        #pragma unroll
        for (int b2 = 0; b2 < 4; b2++) {
            float v0 = db[2*b2][q];
            float v1 = db[2*b2 + 1][q];
            float o0 = dpp_mov<DPP_XOR1>(v0);
            float o1 = dpp_mov<DPP_XOR1>(v1);
            pk[b2] = par ? pkbf(o1, v1) : pkbf(v0, o0);
        }
        if (mq < NNODES)
            xproj_b[mq * 16 + par * 8 + (j >> 1)] =
                make_uint4(pk[0], pk[1], pk[2], pk[3]);
    }
}

// ==================== CSR edge kernel: 8 lanes/edge, 4 ch/lane (R14) =======
// 7-variant-confirmed local optimum: 32 VGPR / ~71% occupancy is the
// latency-hiding mechanism; any ILP added at register cost loses
// (R13/R16/R18/R22 all measured worse).
__global__ __launch_bounds__(256) void edge_csr_k(
    const int2* __restrict__ sorted2, const int* __restrict__ offs,
    const float* __restrict__ psrc, const float* __restrict__ pdst,
    const unsigned* __restrict__ t1b, const unsigned* __restrict__ t2b,
    const uint4* __restrict__ xproj_b, const float* __restrict__ selfp,
    const float* __restrict__ wcomp_l,
    const float* __restrict__ Bw, const float* __restrict__ Bb,
    float* __restrict__ h_next)
{
    // XCD-bijective swizzle: 25000 blocks, 25000 % 8 == 0.
    const int CPX = 25000 / 8;
    int bid = (int)blockIdx.x;
    bid = (bid % 8) * CPX + bid / 8;

    const int wib  = threadIdx.x >> 6;
    const int lane = threadIdx.x & 63;
    const int grp  = lane >> 3;          // edge slot 0..7
    const int ci   = lane & 7;           // channel quad 0..7
    const int c4   = ci * 4;
    const int n    = bid * 4 + wib;

    const int start = offs[n];
    const int end   = (n == NNODES - 1) ? NEDGES : offs[n + 1];
    const float4 bw = *(const float4*)(Bw + c4);
    const float bb = Bb[0];
    const float4 pd = *(const float4*)(pdst + n * 32 + c4);

    int e = start + grp;
    int2 rec = sorted2[(e < end) ? e : start];
    bool valid = (e < end);

    v2f acc01 = {0.f, 0.f}, acc23 = {0.f, 0.f};
    for (int e0 = start; e0 < end; e0 += 8) {
        int2 cur = rec;
        bool cv = valid;
        int en = e + 8;
        valid = (en < end);
        rec = sorted2[valid ? en : start];
        e = en;

        int s16 = cur.x;
        int et  = cur.y & 0xffff;
        int el  = cur.y >> 16;

        float4 ps  = *(const float4*)(psrc + s16 * 2 + c4);
        uint4  xlo = xproj_b[s16 + ci * 2];
        uint4  xhi = xproj_b[s16 + ci * 2 + 1];
        uint2  t1u = *(const uint2*)(t1b + et * 16 + ci * 2);
        uint2  t2u = *(const uint2*)(t2b + el * 16 + ci * 2);
        float4 c   = *(const float4*)(wcomp_l + et * 4);

        v2f t1a = bf2f(t1u.x), t1c = bf2f(t1u.y);
        v2f t2a = bf2f(t2u.x), t2c = bf2f(t2u.y);
        float z0 = fmaxf(ps.x + pd.x + t1a.x + t2a.x, 0.f);
        float z1 = fmaxf(ps.y + pd.y + t1a.y + t2a.y, 0.f);
        float z2 = fmaxf(ps.z + pd.z + t1c.x + t2c.x, 0.f);
        float z3 = fmaxf(ps.w + pd.w + t1c.y + t2c.y, 0.f);
        float d = fmaf(z0, bw.x, fmaf(z1, bw.y, fmaf(z2, bw.z, z3 * bw.w)));
        d = dpp_add<DPP_XOR1>(d);
        d = dpp_add<DPP_XOR2>(d);
        d = dpp_add<DPP_HMIR>(d);
        float a = __builtin_amdgcn_rcpf(1.f + __expf(-(d + bb)));
        a = cv ? a : 0.f;

        v2f b0 = bf2f(xlo.x), b1 = bf2f(xlo.y), b2 = bf2f(xlo.z), b3 = bf2f(xlo.w);
        v2f m01 = c.x * b0 + c.y * b1 + c.z * b2 + c.w * b3;
        v2f g0 = bf2f(xhi.x), g1 = bf2f(xhi.y), g2 = bf2f(xhi.z), g3 = bf2f(xhi.w);
        v2f m23 = c.x * g0 + c.y * g1 + c.z * g2 + c.w * g3;
        acc01 += a * m01;
        acc23 += a * m23;
    }
    #pragma unroll
    for (int s = 8; s <= 32; s <<= 1) {
        acc01.x += __shfl_xor(acc01.x, s);
        acc01.y += __shfl_xor(acc01.y, s);
        acc23.x += __shfl_xor(acc23.x, s);
        acc23.y += __shfl_xor(acc23.y, s);
    }
    if (lane < 8) {
        float4 sp = *(const float4*)(selfp + n * 32 + c4);
        float4 hv;
        hv.x = fmaxf(acc01.x + sp.x, 0.f);
        hv.y = fmaxf(acc01.y + sp.y, 0.f);
        hv.z = fmaxf(acc23.x + sp.z, 0.f);
        hv.w = fmaxf(acc23.y + sp.w, 0.f);
        *(float4*)(h_next + n * 32 + c4) = hv;
    }
}

// ==================== per-graph mean (8 slices) + head/tail (y=8) ==========
__global__ __launch_bounds__(256) void mean_ht_k(
    const float* __restrict__ h, const int* __restrict__ head_ids,
    const int* __restrict__ tail_ids, float* __restrict__ g_acc,
    float* __restrict__ head_buf, float* __restrict__ tail_buf, int l)
{
    int g  = blockIdx.x;
    int sl = blockIdx.y;
    int i  = threadIdx.x & 31;
    if (sl == 8) {
        if (threadIdx.x < 32)
            head_buf[g*96 + l*32 + i] = h[head_ids[g]*32 + i];
        else if (threadIdx.x < 64)
            tail_buf[g*96 + l*32 + i] = h[tail_ids[g]*32 + i];
        return;
    }
    int sub = threadIdx.x >> 5;
    float acc = 0.f;
    for (int k = sub; k < 125; k += 8)
        acc += h[(g*NPER + sl*125 + k)*32 + i];
    __shared__ float red[8][32];
    red[sub][i] = acc;
    __syncthreads();
    if (threadIdx.x < 32) {
        float s2 = 0.f;
        #pragma unroll
        for (int k = 0; k < 8; k++) s2 += red[k][threadIdx.x];
        atomicAdd(&g_acc[g*96 + l*32 + threadIdx.x], s2 * (1.0f/NPER));
    }
}

// ==================== final readout ====================
__global__ __launch_bounds__(64) void readout_k(
    const float* __restrict__ g_acc, const float* __restrict__ head_buf,
    const float* __restrict__ tail_buf, const float* __restrict__ rel_tab,
    const int* __restrict__ rel_labels, const float* __restrict__ fc_w,
    const float* __restrict__ fc_b, float* __restrict__ out)
{
    int g = blockIdx.x;
    int t = threadIdx.x;
    float s = 0.f;
    for (int idx = t; idx < 320; idx += 64) {
        float v;
        if (idx < 96)       v = g_acc[g*96 + idx];
        else if (idx < 192) v = head_buf[g*96 + idx - 96];
        else if (idx < 288) v = tail_buf[g*96 + idx - 192];
        else                v = rel_tab[rel_labels[g]*32 + (idx - 288)];
        s += v * fc_w[idx];
    }
    s += __shfl_xor(s, 1, 64);
    s += __shfl_xor(s, 2, 64);
    s += __shfl_xor(s, 4, 64);
    s += __shfl_xor(s, 8, 64);
    s += __shfl_xor(s, 16, 64);
    s += __shfl_xor(s, 32, 64);
    if (t == 0) out[g] = s + fc_b[0];
}

extern "C" void kernel_launch(void* const* d_in, const int* in_sizes, int n_in,
                              void* d_out, int out_size, void* d_ws, size_t ws_size,
                              hipStream_t stream) {
    const float* feat        = (const float*)d_in[0];
    const float* basis       = (const float*)d_in[1];   // [3,4,32,32]
    const float* w_comp      = (const float*)d_in[2];   // [3,200,4]
    const float* self_loop_w = (const float*)d_in[3];   // [3,32,32]
    const float* A_w         = (const float*)d_in[4];   // [3,128,32]
    const float* A_b         = (const float*)d_in[5];   // [3,32]
    const float* B_w         = (const float*)d_in[6];   // [3,32,1]
    const float* B_b         = (const float*)d_in[7];   // [3,1]
    const float* attn_tab    = (const float*)d_in[8];   // [200,32]
    const float* rel_tab     = (const float*)d_in[9];   // [200,32]
    const float* fc_w        = (const float*)d_in[10];  // [320,1]
    const float* fc_b        = (const float*)d_in[11];  // [1]
    const int* src        = (const int*)d_in[12];
    const int* dst        = (const int*)d_in[13];
    const int* etype      = (const int*)d_in[14];
    const int* elabel     = (const int*)d_in[15];
    const int* head_ids   = (const int*)d_in[17];
    const int* tail_ids   = (const int*)d_in[18];
    const int* rel_labels = (const int*)d_in[19];

    float* ws = (float*)d_ws;
    size_t off = 0;
    float* h0    = ws + off; off += (size_t)NNODES * 32;
    float* h1    = ws + off; off += (size_t)NNODES * 32;
    uint4* xproj_b = (uint4*)(ws + off); off += (size_t)NNODES * 64;  // 256B/node
    float* psrc  = ws + off; off += (size_t)NNODES * 32;
    float* pdst  = ws + off; off += (size_t)NNODES * 32;
    float* selfp = ws + off; off += (size_t)NNODES * 32;
    unsigned* t1b = (unsigned*)(ws + off); off += 3 * 3200;
    unsigned* t2b = (unsigned*)(ws + off); off += 3 * 3200;
    uint4* bfrag  = (uint4*)(ws + off);   off += 3 * 14 * 64 * 4;
    float* g_acc    = ws + off; off += NGRAPH * 96;
    float* head_buf = ws + off; off += NGRAPH * 96;
    float* tail_buf = ws + off; off += NGRAPH * 96;
    int* count  = (int*)(ws + off); off += NNODES;
    int* offs   = (int*)(ws + off); off += NNODES;
    int* cursor = (int*)(ws + off); off += NNODES;
    off = (off + 3) & ~(size_t)3;               // 16 B align
    int2* sorted2 = (int2*)(ws + off); off += (size_t)NEDGES * 2;

    // ---- one-time per call: CSR by dst + weight frags + rel tables ----
    zero2_k<<<(NNODES + 255)/256, 256, 0, stream>>>(count, g_acc);
    hist_k<<<(NEDGES + 255)/256, 256, 0, stream>>>(dst, count);
    scan_k<<<NGRAPH, 1024, 0, stream>>>(count, offs, cursor);
    scatter_k<<<(NEDGES + 255)/256, 256, 0, stream>>>(src, dst, etype, elabel,
                                                      cursor, sorted2);
    dim3 wgrid(14, 3);
    wfrag_k<<<wgrid, 64, 0, stream>>>(basis, self_loop_w, A_w, bfrag);
    dim3 rgrid(50, 3);
    rel3_k<<<rgrid, 256, 0, stream>>>(attn_tab, A_w, A_b, t1b, t2b);

    const float* hcur = feat;
    float* hbufs[2] = { h0, h1 };
    for (int l = 0; l < 3; l++) {
        node_mfma_k<<<(NNODES + 63)/64, 256, 0, stream>>>(
            hcur, bfrag + (size_t)l*14*64, xproj_b, psrc, pdst, selfp);
        float* hn = hbufs[l & 1];
        edge_csr_k<<<NNODES/4, 256, 0, stream>>>(
            sorted2, offs, psrc, pdst, t1b + l*3200, t2b + l*3200,
            xproj_b, selfp, w_comp + (size_t)l*800,
            B_w + (size_t)l*32, B_b + l, hn);
        dim3 mgrid(NGRAPH, 9);
        mean_ht_k<<<mgrid, 256, 0, stream>>>(
            hn, head_ids, tail_ids, g_acc, head_buf, tail_buf, l);
        hcur = hn;
    }
    readout_k<<<NGRAPH, 64, 0, stream>>>(
        g_acc, head_buf, tail_buf, rel_tab, rel_labels, fc_w, fc_b, (float*)d_out);
}